// Round 12
// baseline (180.733 us; speedup 1.0000x reference)
//
#include <hip/hip_runtime.h>

// CTC batch cost, B=64 T=1024 C=512 (blank=C-1) L=128, S=2L+1=257.
// Fused producer/consumer single kernel:
//   - 64 scanner blocks (1 wave each): R7-proven q-ratio probability-domain
//     forward scan. Lane l owns states 4l..4l+3 as X=(s0,s2),Y=(s1,s3):
//     s3=shr1(Y.y); S=(s3,Y.x); nY=((X+Y)+SK*S)*Q; X+=S; pS+=Y.y (state 256,
//     lane 63). Exact power-of-2 rescale every 16 steps via DPP max-reduce.
//     loss = -(log(p255+p256) + ksum*ln2 + sum_t log eb(t)).
//   - 1024 producer blocks (4 waves): each handles 4 chunks (16 rows each)
//     of one batch in time order: rowsum + q=(y_lab+eps)/(y_blank+eps)
//     gather (bf16-packed) + log eb accumulation -> atomicAdd + release flag.
//   Scanner: agent-scope ACQUIRE on the flag, then PLAIN q loads (the
//   acquire fence orders/invalidates for all later loads — R11's per-element
//   atomic data loads serialized at ~500cy each and spilled the buffers).
//   Flags+sumlog zeroed per launch by a tiny kernel (capture-safe).

#define EPSF 1e-7f
static constexpr int NB = 64, NT = 1024, NC = 512, NL = 128;
static constexpr int CH = 16;           // rows per flag-chunk
static constexpr int NCHK = NT / CH;    // 64 chunks per batch
static constexpr int KPB = 16;          // producer blocks per batch
static constexpr int PRODB = NB * KPB;  // 1024
static constexpr int RND = NCHK / KPB;  // 4 chunks per producer block

typedef unsigned int uint32;
typedef float v2f __attribute__((ext_vector_type(2)));

__device__ __forceinline__ unsigned short rn_bf16(float x) {
    uint32 b = __float_as_uint(x);
    return (unsigned short)((b + 0x7FFFu + ((b >> 16) & 1u)) >> 16);
}

// ---------------- DPP helpers (verified: 0x138 shr1, row_shr/bcast) ------
__device__ __forceinline__ float dpp_shr1(float x) {  // lane l <- l-1, 0@0
    return __int_as_float(__builtin_amdgcn_update_dpp(
        0, __float_as_int(x), 0x138, 0xF, 0xF, true));
}

__device__ __forceinline__ float dpp_wave_max(float m) {
#define DPPMAX_(ctrl)                                                     \
    m = fmaxf(m, __int_as_float(__builtin_amdgcn_update_dpp(              \
                     0, __float_as_int(m), ctrl, 0xF, 0xF, true)))
    DPPMAX_(0x111); DPPMAX_(0x112); DPPMAX_(0x114); DPPMAX_(0x118);
    DPPMAX_(0x142); DPPMAX_(0x143);
#undef DPPMAX_
    return __int_as_float(
        __builtin_amdgcn_readlane(__float_as_int(m), 63));
}

// ---------------- flag/sumlog zeroing (per launch; capture-safe) ---------
__global__ void ctc_zero(uint32* __restrict__ f, int n) {
    int i = blockIdx.x * 256 + threadIdx.x;
    if (i < n) f[i] = 0u;
}

// ---------------- fused producer + scanner kernel ------------------------
__global__ __launch_bounds__(256) void ctc_fused(
    const float* __restrict__ Yp, const int* __restrict__ y_true,
    uint32* __restrict__ qlab, uint32* __restrict__ flags,
    float* __restrict__ sumlog, float* __restrict__ out) {
    __shared__ float sl[4];
    const int bid = blockIdx.x;

    if (bid >= NB) {
        // ================= producer =================
        const int p = bid - NB;
        const int b = p & (NB - 1);
        const int k = p >> 6;  // 0..KPB-1; k=0 blocks dispatch first
        const int lane = threadIdx.x & 63;
        const int wslot = threadIdx.x >> 6;  // 0..3
        int2 lp = *reinterpret_cast<const int2*>(y_true + b * NL + lane * 2);

        for (int r = 0; r < RND; ++r) {
            int c = k + r * KPB;  // time-ordered chunks
            float wlog = 0.0f;
#pragma unroll
            for (int i = 0; i < 4; ++i) {
                int w = b * NT + c * CH + wslot * 4 + i;
                const float* row = Yp + (size_t)w * NC;
                float4 v0 = *reinterpret_cast<const float4*>(row + lane * 4);
                float4 v1 =
                    *reinterpret_cast<const float4*>(row + NC / 2 + lane * 4);
                float s = ((v0.x + v0.y) + (v0.z + v0.w)) +
                          ((v1.x + v1.y) + (v1.z + v1.w));
#pragma unroll
                for (int d = 1; d < 64; d <<= 1) s += __shfl_xor(s, d);
                float rb = row[NC - 1] + EPSF;  // wave-uniform
                float rbi = 1.0f / rb;
                float qx = (row[lp.x] + EPSF) * rbi;
                float qy = (row[lp.y] + EPSF) * rbi;
                qlab[(size_t)w * (NL / 2) + lane] =
                    (uint32)rn_bf16(qx) | ((uint32)rn_bf16(qy) << 16);
                wlog += logf(rb * (1.0f / (s + NC * EPSF)));  // log eb
            }
            if (lane == 0) sl[wslot] = wlog;
            __syncthreads();
            if (threadIdx.x == 0) {
                atomicAdd(sumlog + b, sl[0] + sl[1] + sl[2] + sl[3]);
                __hip_atomic_store(flags + b * NCHK + c, 1u, __ATOMIC_RELEASE,
                                   __HIP_MEMORY_SCOPE_AGENT);
            }
            __syncthreads();
        }
        return;
    }

    // ================= scanner (R7-proven core) =================
    if (threadIdx.x >= 64) return;
    const int b = bid;
    const int l = threadIdx.x;
    const int* lab = y_true + b * NL;

    int lab_m1 = (l == 0) ? -1 : lab[2 * l - 1];
    int lab0 = lab[2 * l];
    int lab1 = lab[2 * l + 1];
    v2f SK = {(lab0 != lab_m1) ? 1.0f : 0.0f, (lab1 != lab0) ? 1.0f : 0.0f};

    v2f X = {(l == 0) ? 1.0f : 0.0f, 0.0f};  // unit mass pre-state-0
    v2f Y = {0.0f, 0.0f};
    float pS = 0.0f;
    int ksum = 0;

    const uint32* fb = flags + b * NCHK;
    const uint32* qb = qlab + (size_t)b * NT * (NL / 2) + l;
    uint32 La[CH], Lb[CH];

    auto peek = [&](int c) -> uint32 {
        return __hip_atomic_load(fb + c, __ATOMIC_RELAXED,
                                 __HIP_MEMORY_SCOPE_AGENT);
    };
    auto waitf = [&](int c) {
        while (__hip_atomic_load(fb + c, __ATOMIC_ACQUIRE,
                                 __HIP_MEMORY_SCOPE_AGENT) == 0u)
            __builtin_amdgcn_s_sleep(2);
    };
    auto loadq = [&](int c, uint32(&L)[CH]) {
        // PLAIN loads: each loadq(c) is program-ordered after waitf(c)'s
        // agent-scope acquire (fence covers subsequent ordinary loads).
        const uint32* base = qb + (size_t)c * CH * (NL / 2);
#pragma unroll
        for (int j = 0; j < CH; ++j) L[j] = base[(size_t)j * (NL / 2)];
    };
    auto process = [&](uint32(&L)[CH]) {
#pragma unroll
        for (int j = 0; j < CH; ++j) {
            float s3 = dpp_shr1(Y.y);  // state 4l-1 (old)
            v2f Qv = {__uint_as_float(L[j] << 16),
                      __uint_as_float(L[j] & 0xFFFF0000u)};
            v2f S = {s3, Y.x};
            v2f T = X + Y;
            pS += Y.y;  // lane63: state 256 += state 255
            v2f nY = (T + SK * S) * Qv;
            X = X + S;
            Y = nY;
        }
        // exact power-of-2 rescale every 16 steps
        float m = fmaxf(fmaxf(X.x, Y.x), fmaxf(X.y, Y.y));
        m = fmaxf(m, (l == 63) ? pS : 0.0f);
        float mall = fmaxf(dpp_wave_max(m), 1e-30f);
        int e = (int)(__float_as_uint(mall) >> 23) - 127;
        float sc = __uint_as_float((uint32)(127 - e) << 23);
        X = X * sc; Y = Y * sc; pS *= sc;
        ksum += e;
    };

    // invariant at loop head: flags c and c+1 confirmed; La = chunk c
    waitf(0);
    waitf(1);
    loadq(0, La);
    for (int c = 0; c < NCHK; c += 2) {
        uint32 f2 = (c + 2 < NCHK) ? peek(c + 2) : 1u;  // issue early
        loadq(c + 1, Lb);
        __builtin_amdgcn_sched_barrier(0);
        process(La);
        __builtin_amdgcn_sched_barrier(0);
        if (f2 == 0u) waitf(c + 2);  // hidden under process in common case
        __builtin_amdgcn_sched_barrier(0);
        uint32 f3 = (c + 3 < NCHK) ? peek(c + 3) : 1u;
        if (c + 2 < NCHK) loadq(c + 2, La);
        __builtin_amdgcn_sched_barrier(0);
        process(Lb);
        __builtin_amdgcn_sched_barrier(0);
        if (f3 == 0u) waitf(c + 3);
        __builtin_amdgcn_sched_barrier(0);
    }

    if (l == 63) {
        float sred = __hip_atomic_load(sumlog + b, __ATOMIC_ACQUIRE,
                                       __HIP_MEMORY_SCOPE_AGENT);
        float tot = Y.y + pS;  // alpha_T[255] + alpha_T[256] (hat-space)
        out[b] = -(logf(tot) + (float)ksum * 0.69314718055994531f + sred);
    }
}

// ---------------- fallback (ws too small): legacy eb-form scan -----------
__global__ __launch_bounds__(256) void ctc_prep0(const float* __restrict__ Y,
                                                 float* __restrict__ invb) {
    const int lane = threadIdx.x & 63;
    const int wslot = threadIdx.x >> 6;
    const int nw = gridDim.x * 4;
    for (int w = blockIdx.x * 4 + wslot; w < NB * NT; w += nw) {
        const float* row = Y + (size_t)w * NC;
        float4 v0 = *reinterpret_cast<const float4*>(row + lane * 4);
        float4 v1 = *reinterpret_cast<const float4*>(row + NC / 2 + lane * 4);
        float s = ((v0.x + v0.y) + (v0.z + v0.w)) +
                  ((v1.x + v1.y) + (v1.z + v1.w));
#pragma unroll
        for (int d = 1; d < 64; d <<= 1) s += __shfl_xor(s, d);
        if (lane == 0) invb[w] = 256.0f / (s + NC * EPSF);
    }
}

__global__ __launch_bounds__(64) void ctc_rec0(const float* __restrict__ A,
                                               const float* __restrict__ Bv,
                                               const int* __restrict__ y_true,
                                               float* __restrict__ out) {
    const int b = blockIdx.x;
    const int l = threadIdx.x;
    const int* lab = y_true + b * NL;

    int lab_m1 = (l == 0) ? -1 : lab[2 * l - 1];
    int lab0 = lab[2 * l];
    int lab1 = lab[2 * l + 1];
    float sk0 = (lab0 != lab_m1) ? 1.0f : 0.0f;
    float sk1 = (lab1 != lab0) ? 1.0f : 0.0f;

    float p0 = (l == 0) ? 1.0f : 0.0f;
    float p1 = 0.0f, p2 = 0.0f, p3 = 0.0f, pS = 0.0f;
    int ksum = 0;

    for (int t = 0; t < NT; t++) {
        const float* base = A + ((size_t)b * NT + t) * NC;
        float iv = Bv[b * NT + t];
        float eb = (base[NC - 1] + EPSF) * iv;
        float ex = (base[lab0] + EPSF) * iv;
        float ey = (base[lab1] + EPSF) * iv;
        float s3 = dpp_shr1(p3);
        float n0 = (p0 + s3) * eb;
        float n1 = (p1 + p0 + sk0 * s3) * ex;
        float n2 = (p2 + p1) * eb;
        float n3 = (p3 + p2 + sk1 * p1) * ey;
        pS = (pS + p3) * eb;
        p0 = n0; p1 = n1; p2 = n2; p3 = n3;
        if ((t & 15) == 15) {
            float m = fmaxf(fmaxf(p0, p1), fmaxf(p2, p3));
            m = fmaxf(m, (l == 63) ? pS : 0.0f);
            float mall = fmaxf(dpp_wave_max(m), 1e-30f);
            int e = (int)(__float_as_uint(mall) >> 23) - 127;
            float sc = __uint_as_float((uint32)(127 - e) << 23);
            p0 *= sc; p1 *= sc; p2 *= sc; p3 *= sc; pS *= sc;
            ksum += e;
        }
    }

    if (l == 63) {
        float tot = p3 + pS;
        out[b] = -(logf(tot) + (float)(ksum - 8192) * 0.69314718055994531f);
    }
}

extern "C" void kernel_launch(void* const* d_in, const int* in_sizes, int n_in,
                              void* d_out, int out_size, void* d_ws, size_t ws_size,
                              hipStream_t stream) {
    const int* y_true = (const int*)d_in[0];
    const float* y_pred = (const float*)d_in[1];
    float* out = (float*)d_out;

    const size_t qlab_bytes = (size_t)NB * NT * (NL / 2) * sizeof(uint32);  // 16 MiB
    const int nflag = NB * NCHK;             // 4096
    const int nzero = nflag + NB;            // + sumlog
    const size_t need = qlab_bytes + (size_t)nzero * 4;

    if (ws_size >= need) {
        uint32* qlab = (uint32*)d_ws;
        uint32* flags = (uint32*)((char*)d_ws + qlab_bytes);
        float* sumlog = (float*)(flags + nflag);
        ctc_zero<<<(nzero + 255) / 256, 256, 0, stream>>>(flags, nzero);
        ctc_fused<<<NB + PRODB, 256, 0, stream>>>(y_pred, y_true, qlab, flags,
                                                  sumlog, out);
    } else {
        float* invb = (float*)d_ws;
        ctc_prep0<<<2048, 256, 0, stream>>>(y_pred, invb);
        ctc_rec0<<<NB, 64, 0, stream>>>(y_pred, invb, y_true, out);
    }
}

// Round 13
// 72.124 us; speedup vs baseline: 2.5059x; 2.5059x over previous
//
#include <hip/hip_runtime.h>

// CTC batch cost, B=64 T=1024 C=512 (blank=C-1) L=128, S=2L+1=257.
// PHASE-PIPELINED q-ratio probability-domain forward scan.
//   T split into P=4 phases of 256 steps. Kernel k = [scan phase k-1 on 64
//   blocks] || [prep phase k on 192 blocks]. No runtime sync: the scan
//   reads q written by the PREVIOUS kernel (kernel boundary = barrier +
//   visibility). R11/R12 evidence: intra-kernel agent-scope release/acquire
//   flags cost ~270us in L2 writeback/invalidate traffic - never again.
// Scan math (R7-proven): lane l owns states 4l..4l+3 as X=(s0,s2),Y=(s1,s3):
//   s3=shr1(Y.y); S=(s3,Y.x); nY=((X+Y)+SK*S)*Q; X+=S; pS+=Y.y (state 256,
//   lane 63). q = (y_lab+eps)/(y_blank+eps) staged as f32 float2 (no unpack).
//   Exact power-of-2 rescale every 16 steps via DPP max-reduce.
//   loss = -(log(p255+p256) + ksum*ln2 + sum_t log eb(t)).
// Scanner state (X,Y per lane; pS,sred,ksum per batch) carried across
// kernels in ws. Two 8MiB q slots ping-pong between phases.

#define EPSF 1e-7f
static constexpr int NB = 64, NT = 1024, NC = 512, NL = 128;
static constexpr int P = 4, TPH = NT / P;    // 256 t-steps per phase
static constexpr int CH = 16, CPP = TPH / CH;  // 16 chunks per phase
static constexpr size_t SLOTF = (size_t)NB * TPH * NL;  // floats per q slot

typedef unsigned int uint32;
typedef float v2f __attribute__((ext_vector_type(2)));

// ---------------- DPP helpers (verified: 0x138 shr1, row_shr/bcast) ------
__device__ __forceinline__ float dpp_shr1(float x) {  // lane l <- l-1, 0@0
    return __int_as_float(__builtin_amdgcn_update_dpp(
        0, __float_as_int(x), 0x138, 0xF, 0xF, true));
}

__device__ __forceinline__ float dpp_wave_max(float m) {
#define DPPMAX_(ctrl)                                                     \
    m = fmaxf(m, __int_as_float(__builtin_amdgcn_update_dpp(              \
                     0, __float_as_int(m), ctrl, 0xF, 0xF, true)))
    DPPMAX_(0x111); DPPMAX_(0x112); DPPMAX_(0x114); DPPMAX_(0x118);
    DPPMAX_(0x142); DPPMAX_(0x143);
#undef DPPMAX_
    return __int_as_float(
        __builtin_amdgcn_readlane(__float_as_int(m), 63));
}

__device__ __forceinline__ float dpp_wave_sum63(float v) {  // valid lane 63
#define DPPADD_(ctrl)                                                     \
    v += __int_as_float(__builtin_amdgcn_update_dpp(                      \
        0, __float_as_int(v), ctrl, 0xF, 0xF, true))
    DPPADD_(0x111); DPPADD_(0x112); DPPADD_(0x114); DPPADD_(0x118);
    DPPADD_(0x142); DPPADD_(0x143);
#undef DPPADD_
    return v;
}

// ---------------- phase kernel: [scan sp] || [prep pp] -------------------
// sp in [-1, P): -1 = no scan this launch. pp in [0, P]: P = no prep.
__global__ __launch_bounds__(256) void ctc_phase(
    const float* __restrict__ Yp, const int* __restrict__ y_true,
    float* __restrict__ qring, float* __restrict__ eblank,
    float4* __restrict__ stV, float4* __restrict__ stScal,
    int* __restrict__ kint, float* __restrict__ out, int sp, int pp) {
    const int bid = blockIdx.x;

    if (sp < 0 || bid >= NB) {
        // ================= producer: prep phase pp =================
        if (pp >= P) return;
        const int lane = threadIdx.x & 63;
        const int wv = threadIdx.x >> 6;  // 0..3
        const int pbid = (sp < 0) ? bid : (bid - NB);
        const int npb = (sp < 0) ? gridDim.x : (gridDim.x - NB);
        float* qs = qring + (size_t)(pp & 1) * SLOTF;

        for (int i = pbid * 4 + wv; i < NB * TPH; i += npb * 4) {
            int b = i >> 8;           // TPH = 256
            int tl = i & (TPH - 1);
            int w = b * NT + pp * TPH + tl;
            const float* row = Yp + (size_t)w * NC;

            float4 v0 = *reinterpret_cast<const float4*>(row + lane * 4);
            float4 v1 =
                *reinterpret_cast<const float4*>(row + NC / 2 + lane * 4);
            float s = ((v0.x + v0.y) + (v0.z + v0.w)) +
                      ((v1.x + v1.y) + (v1.z + v1.w));
#pragma unroll
            for (int d = 1; d < 64; d <<= 1) s += __shfl_xor(s, d);

            float rb = row[NC - 1] + EPSF;  // wave-uniform
            float rbi = 1.0f / rb;
            int2 lp =
                *reinterpret_cast<const int2*>(y_true + b * NL + lane * 2);
            float2 q;
            q.x = (row[lp.x] + EPSF) * rbi;
            q.y = (row[lp.y] + EPSF) * rbi;
            *reinterpret_cast<float2*>(qs + ((size_t)b * TPH + tl) * NL +
                                       2 * lane) = q;
            if (lane == 0)
                eblank[w] = rb * (1.0f / (s + NC * EPSF));  // blank prob
        }
        return;
    }

    // ================= scanner: scan phase sp (R7-proven core) ==========
    if (threadIdx.x >= 64) return;
    const int b = bid;
    const int l = threadIdx.x;
    const bool is63 = (l == 63);
    const int* lab = y_true + b * NL;

    int lab_m1 = (l == 0) ? -1 : lab[2 * l - 1];
    int lab0 = lab[2 * l];
    int lab1 = lab[2 * l + 1];
    v2f SK = {(lab0 != lab_m1) ? 1.0f : 0.0f, (lab1 != lab0) ? 1.0f : 0.0f};

    v2f X, Y;
    float pS, sred;
    int ksum;
    if (sp == 0) {
        X = v2f{(l == 0) ? 1.0f : 0.0f, 0.0f};  // unit mass pre-state-0
        Y = v2f{0.0f, 0.0f};
        pS = 0.0f;
        sred = 0.0f;
        ksum = 0;
    } else {
        float4 v = stV[b * 64 + l];
        X = v2f{v.x, v.y};
        Y = v2f{v.z, v.w};
        float4 sc = stScal[b];
        pS = is63 ? sc.x : 0.0f;
        sred = is63 ? sc.y : 0.0f;
        ksum = kint[b];
    }

    // this phase's sum_t log eb(t): 4 values per lane, wave-reduce
    {
        float slog = 0.0f;
#pragma unroll
        for (int k = 0; k < TPH / 64; k++)
            slog += logf(eblank[b * NT + sp * TPH + k * 64 + l]);
        sred += dpp_wave_sum63(slog);  // lane 63 meaningful
    }

    const float* qs =
        qring + (size_t)(sp & 1) * SLOTF + (size_t)b * TPH * NL + 2 * l;
    float2 La[CH], Lb[CH];

    auto load = [&](int c, float2(&L)[CH]) {
        const float* base = qs + (size_t)c * CH * NL;
#pragma unroll
        for (int j = 0; j < CH; ++j)
            L[j] = *reinterpret_cast<const float2*>(base + (size_t)j * NL);
    };
    auto process = [&](float2(&L)[CH]) {
#pragma unroll
        for (int j = 0; j < CH; ++j) {
            float s3 = dpp_shr1(Y.y);  // state 4l-1 (old)
            v2f Qv = {L[j].x, L[j].y};
            v2f S = {s3, Y.x};
            v2f T = X + Y;
            pS += Y.y;  // lane63: state 256 += state 255
            v2f nY = (T + SK * S) * Qv;
            X = X + S;
            Y = nY;
        }
        // exact power-of-2 rescale every 16 steps
        float m = fmaxf(fmaxf(X.x, Y.x), fmaxf(X.y, Y.y));
        m = fmaxf(m, is63 ? pS : 0.0f);
        float mall = fmaxf(dpp_wave_max(m), 1e-30f);
        int e = (int)(__float_as_uint(mall) >> 23) - 127;
        float sc = __uint_as_float((uint32)(127 - e) << 23);
        X = X * sc; Y = Y * sc; pS *= sc;
        ksum += e;
    };

    load(0, La);
    for (int c = 0; c < CPP; c += 2) {
        __builtin_amdgcn_sched_barrier(0);
        if (c + 1 < CPP) load(c + 1, Lb);
        __builtin_amdgcn_sched_barrier(0);
        process(La);
        __builtin_amdgcn_sched_barrier(0);
        if (c + 2 < CPP) load(c + 2, La);
        __builtin_amdgcn_sched_barrier(0);
        process(Lb);
    }

    if (sp == P - 1) {
        if (is63) {
            float tot = Y.y + pS;  // alpha_T[255] + alpha_T[256] (hat)
            out[b] =
                -(logf(tot) + (float)ksum * 0.69314718055994531f + sred);
        }
    } else {
        stV[b * 64 + l] = make_float4(X.x, X.y, Y.x, Y.y);
        if (is63) {
            stScal[b] = make_float4(pS, sred, 0.0f, 0.0f);
            kint[b] = ksum;
        }
    }
}

// ---------------- fallback (ws too small): legacy eb-form scan -----------
__global__ __launch_bounds__(256) void ctc_prep0(const float* __restrict__ Y,
                                                 float* __restrict__ invb) {
    const int lane = threadIdx.x & 63;
    const int wslot = threadIdx.x >> 6;
    const int nw = gridDim.x * 4;
    for (int w = blockIdx.x * 4 + wslot; w < NB * NT; w += nw) {
        const float* row = Y + (size_t)w * NC;
        float4 v0 = *reinterpret_cast<const float4*>(row + lane * 4);
        float4 v1 = *reinterpret_cast<const float4*>(row + NC / 2 + lane * 4);
        float s = ((v0.x + v0.y) + (v0.z + v0.w)) +
                  ((v1.x + v1.y) + (v1.z + v1.w));
#pragma unroll
        for (int d = 1; d < 64; d <<= 1) s += __shfl_xor(s, d);
        if (lane == 0) invb[w] = 256.0f / (s + NC * EPSF);
    }
}

__global__ __launch_bounds__(64) void ctc_rec0(const float* __restrict__ A,
                                               const float* __restrict__ Bv,
                                               const int* __restrict__ y_true,
                                               float* __restrict__ out) {
    const int b = blockIdx.x;
    const int l = threadIdx.x;
    const int* lab = y_true + b * NL;

    int lab_m1 = (l == 0) ? -1 : lab[2 * l - 1];
    int lab0 = lab[2 * l];
    int lab1 = lab[2 * l + 1];
    float sk0 = (lab0 != lab_m1) ? 1.0f : 0.0f;
    float sk1 = (lab1 != lab0) ? 1.0f : 0.0f;

    float p0 = (l == 0) ? 1.0f : 0.0f;
    float p1 = 0.0f, p2 = 0.0f, p3 = 0.0f, pS = 0.0f;
    int ksum = 0;

    for (int t = 0; t < NT; t++) {
        const float* base = A + ((size_t)b * NT + t) * NC;
        float iv = Bv[b * NT + t];
        float eb = (base[NC - 1] + EPSF) * iv;
        float ex = (base[lab0] + EPSF) * iv;
        float ey = (base[lab1] + EPSF) * iv;
        float s3 = dpp_shr1(p3);
        float n0 = (p0 + s3) * eb;
        float n1 = (p1 + p0 + sk0 * s3) * ex;
        float n2 = (p2 + p1) * eb;
        float n3 = (p3 + p2 + sk1 * p1) * ey;
        pS = (pS + p3) * eb;
        p0 = n0; p1 = n1; p2 = n2; p3 = n3;
        if ((t & 15) == 15) {
            float m = fmaxf(fmaxf(p0, p1), fmaxf(p2, p3));
            m = fmaxf(m, (l == 63) ? pS : 0.0f);
            float mall = fmaxf(dpp_wave_max(m), 1e-30f);
            int e = (int)(__float_as_uint(mall) >> 23) - 127;
            float sc = __uint_as_float((uint32)(127 - e) << 23);
            p0 *= sc; p1 *= sc; p2 *= sc; p3 *= sc; pS *= sc;
            ksum += e;
        }
    }

    if (l == 63) {
        float tot = p3 + pS;
        out[b] = -(logf(tot) + (float)(ksum - 8192) * 0.69314718055994531f);
    }
}

extern "C" void kernel_launch(void* const* d_in, const int* in_sizes, int n_in,
                              void* d_out, int out_size, void* d_ws, size_t ws_size,
                              hipStream_t stream) {
    const int* y_true = (const int*)d_in[0];
    const float* y_pred = (const float*)d_in[1];
    float* out = (float*)d_out;

    const size_t qring_b = 2 * SLOTF * sizeof(float);        // 16 MiB
    const size_t eb_b = (size_t)NB * NT * sizeof(float);     // 256 KiB
    const size_t stV_b = (size_t)NB * 64 * sizeof(float4);   // 64 KiB
    const size_t stS_b = (size_t)NB * sizeof(float4);        // 1 KiB
    const size_t kint_b = (size_t)NB * sizeof(int);
    const size_t need = qring_b + eb_b + stV_b + stS_b + kint_b;

    if (ws_size >= need) {
        char* p = (char*)d_ws;
        float* qring = (float*)p;            p += qring_b;
        float* eblank = (float*)p;           p += eb_b;
        float4* stV = (float4*)p;            p += stV_b;
        float4* stScal = (float4*)p;         p += stS_b;
        int* kint = (int*)p;

        // k=0: prep phase 0 only (all 256 blocks produce)
        ctc_phase<<<256, 256, 0, stream>>>(y_pred, y_true, qring, eblank,
                                           stV, stScal, kint, out, -1, 0);
        // k=1..P-1: scan phase k-1 (64 blocks) || prep phase k (192 blocks)
        for (int k = 1; k < P; ++k)
            ctc_phase<<<256, 256, 0, stream>>>(y_pred, y_true, qring, eblank,
                                               stV, stScal, kint, out, k - 1,
                                               k);
        // final: scan phase P-1 only
        ctc_phase<<<256, 256, 0, stream>>>(y_pred, y_true, qring, eblank,
                                           stV, stScal, kint, out, P - 1, P);
    } else {
        float* invb = (float*)d_ws;
        ctc_prep0<<<2048, 256, 0, stream>>>(y_pred, invb);
        ctc_rec0<<<NB, 64, 0, stream>>>(y_pred, invb, y_true, out);
    }
}

// Round 14
// 57.442 us; speedup vs baseline: 3.1464x; 1.2556x over previous
//
#include <hip/hip_runtime.h>

// CTC batch cost, B=64 T=1024 C=512 (blank=C-1) L=128, S=2L+1=257.
// PHASE-PIPELINED q-ratio probability-domain forward scan.
//   T split into P=4 phases of 256 steps. Middle kernel k = [scan phase k-1
//   on 64 blocks] || [prep phase k on 960 blocks]. No runtime sync: the
//   scan reads q written by the PREVIOUS kernel (kernel boundary = barrier
//   + visibility). R11/R12: intra-kernel agent-scope flags cost ~270us in
//   L2 writeback traffic. R13: 192-block producers (1 wave/SIMD) were
//   TLP-starved at ~2.5TB/s -> widened to 960 blocks (15 waves/CU).
// Scan math (R7-proven): lane l owns states 4l..4l+3 as X=(s0,s2),Y=(s1,s3):
//   s3=shr1(Y.y); S=(s3,Y.x); nY=((X+Y)+SK*S)*Q; X+=S; pS+=Y.y (state 256,
//   lane 63). q = (y_lab+eps)/(y_blank+eps) staged as f32 float2.
//   Exact power-of-2 rescale every 16 steps via DPP max-reduce.
//   loss = -(log(p255+p256) + ksum*ln2 + sum_t log eb(t)).
// Scanner state (X,Y per lane; pS,sred,ksum per batch) carried across
// kernels in ws. Two 8MiB q slots ping-pong between phases.

#define EPSF 1e-7f
static constexpr int NB = 64, NT = 1024, NC = 512, NL = 128;
static constexpr int P = 4, TPH = NT / P;      // 256 t-steps per phase
static constexpr int CH = 16, CPP = TPH / CH;  // 16 chunks per phase
static constexpr int GRID = 1024;              // middle-kernel grid
static constexpr size_t SLOTF = (size_t)NB * TPH * NL;  // floats per q slot

typedef unsigned int uint32;
typedef float v2f __attribute__((ext_vector_type(2)));

// ---------------- DPP helpers (verified: 0x138 shr1, row_shr/bcast) ------
__device__ __forceinline__ float dpp_shr1(float x) {  // lane l <- l-1, 0@0
    return __int_as_float(__builtin_amdgcn_update_dpp(
        0, __float_as_int(x), 0x138, 0xF, 0xF, true));
}

__device__ __forceinline__ float dpp_wave_max(float m) {
#define DPPMAX_(ctrl)                                                     \
    m = fmaxf(m, __int_as_float(__builtin_amdgcn_update_dpp(              \
                     0, __float_as_int(m), ctrl, 0xF, 0xF, true)))
    DPPMAX_(0x111); DPPMAX_(0x112); DPPMAX_(0x114); DPPMAX_(0x118);
    DPPMAX_(0x142); DPPMAX_(0x143);
#undef DPPMAX_
    return __int_as_float(
        __builtin_amdgcn_readlane(__float_as_int(m), 63));
}

__device__ __forceinline__ float dpp_wave_sum63(float v) {  // valid lane 63
#define DPPADD_(ctrl)                                                     \
    v += __int_as_float(__builtin_amdgcn_update_dpp(                      \
        0, __float_as_int(v), ctrl, 0xF, 0xF, true))
    DPPADD_(0x111); DPPADD_(0x112); DPPADD_(0x114); DPPADD_(0x118);
    DPPADD_(0x142); DPPADD_(0x143);
#undef DPPADD_
    return v;
}

// ---------------- phase kernel: [scan sp] || [prep pp] -------------------
// sp in [-1, P): -1 = no scan this launch. pp in [0, P]: P = no prep.
__global__ __launch_bounds__(256) void ctc_phase(
    const float* __restrict__ Yp, const int* __restrict__ y_true,
    float* __restrict__ qring, float* __restrict__ eblank,
    float4* __restrict__ stV, float4* __restrict__ stScal,
    int* __restrict__ kint, float* __restrict__ out, int sp, int pp) {
    const int bid = blockIdx.x;

    if (sp < 0 || bid >= NB) {
        // ================= producer: prep phase pp =================
        if (pp >= P) return;
        const int lane = threadIdx.x & 63;
        const int wv = threadIdx.x >> 6;  // 0..3
        const int pbid = (sp < 0) ? bid : (bid - NB);
        const int npb = (sp < 0) ? gridDim.x : (gridDim.x - NB);
        float* qs = qring + (size_t)(pp & 1) * SLOTF;

        for (int i = pbid * 4 + wv; i < NB * TPH; i += npb * 4) {
            int b = i >> 8;           // TPH = 256
            int tl = i & (TPH - 1);
            int w = b * NT + pp * TPH + tl;
            const float* row = Yp + (size_t)w * NC;

            float4 v0 = *reinterpret_cast<const float4*>(row + lane * 4);
            float4 v1 =
                *reinterpret_cast<const float4*>(row + NC / 2 + lane * 4);
            float s = ((v0.x + v0.y) + (v0.z + v0.w)) +
                      ((v1.x + v1.y) + (v1.z + v1.w));
#pragma unroll
            for (int d = 1; d < 64; d <<= 1) s += __shfl_xor(s, d);

            float rb = row[NC - 1] + EPSF;  // wave-uniform
            float rbi = 1.0f / rb;
            int2 lp =
                *reinterpret_cast<const int2*>(y_true + b * NL + lane * 2);
            float2 q;
            q.x = (row[lp.x] + EPSF) * rbi;
            q.y = (row[lp.y] + EPSF) * rbi;
            *reinterpret_cast<float2*>(qs + ((size_t)b * TPH + tl) * NL +
                                       2 * lane) = q;
            if (lane == 0)
                eblank[w] = rb * (1.0f / (s + NC * EPSF));  // blank prob
        }
        return;
    }

    // ================= scanner: scan phase sp (R7-proven core) ==========
    if (threadIdx.x >= 64) return;
    const int b = bid;
    const int l = threadIdx.x;
    const bool is63 = (l == 63);
    const int* lab = y_true + b * NL;

    int lab_m1 = (l == 0) ? -1 : lab[2 * l - 1];
    int lab0 = lab[2 * l];
    int lab1 = lab[2 * l + 1];
    v2f SK = {(lab0 != lab_m1) ? 1.0f : 0.0f, (lab1 != lab0) ? 1.0f : 0.0f};

    v2f X, Y;
    float pS, sred;
    int ksum;
    if (sp == 0) {
        X = v2f{(l == 0) ? 1.0f : 0.0f, 0.0f};  // unit mass pre-state-0
        Y = v2f{0.0f, 0.0f};
        pS = 0.0f;
        sred = 0.0f;
        ksum = 0;
    } else {
        float4 v = stV[b * 64 + l];
        X = v2f{v.x, v.y};
        Y = v2f{v.z, v.w};
        float4 sc = stScal[b];
        pS = is63 ? sc.x : 0.0f;
        sred = is63 ? sc.y : 0.0f;
        ksum = kint[b];
    }

    // this phase's sum_t log eb(t): 4 values per lane, wave-reduce
    {
        float slog = 0.0f;
#pragma unroll
        for (int k = 0; k < TPH / 64; k++)
            slog += logf(eblank[b * NT + sp * TPH + k * 64 + l]);
        sred += dpp_wave_sum63(slog);  // lane 63 meaningful
    }

    const float* qs =
        qring + (size_t)(sp & 1) * SLOTF + (size_t)b * TPH * NL + 2 * l;
    float2 La[CH], Lb[CH];

    auto load = [&](int c, float2(&L)[CH]) {
        const float* base = qs + (size_t)c * CH * NL;
#pragma unroll
        for (int j = 0; j < CH; ++j)
            L[j] = *reinterpret_cast<const float2*>(base + (size_t)j * NL);
    };
    auto process = [&](float2(&L)[CH]) {
#pragma unroll
        for (int j = 0; j < CH; ++j) {
            float s3 = dpp_shr1(Y.y);  // state 4l-1 (old)
            v2f Qv = {L[j].x, L[j].y};
            v2f S = {s3, Y.x};
            v2f T = X + Y;
            pS += Y.y;  // lane63: state 256 += state 255
            v2f nY = (T + SK * S) * Qv;
            X = X + S;
            Y = nY;
        }
        // exact power-of-2 rescale every 16 steps
        float m = fmaxf(fmaxf(X.x, Y.x), fmaxf(X.y, Y.y));
        m = fmaxf(m, is63 ? pS : 0.0f);
        float mall = fmaxf(dpp_wave_max(m), 1e-30f);
        int e = (int)(__float_as_uint(mall) >> 23) - 127;
        float sc = __uint_as_float((uint32)(127 - e) << 23);
        X = X * sc; Y = Y * sc; pS *= sc;
        ksum += e;
    };

    load(0, La);
    for (int c = 0; c < CPP; c += 2) {
        __builtin_amdgcn_sched_barrier(0);
        if (c + 1 < CPP) load(c + 1, Lb);
        __builtin_amdgcn_sched_barrier(0);
        process(La);
        __builtin_amdgcn_sched_barrier(0);
        if (c + 2 < CPP) load(c + 2, La);
        __builtin_amdgcn_sched_barrier(0);
        process(Lb);
    }

    if (sp == P - 1) {
        if (is63) {
            float tot = Y.y + pS;  // alpha_T[255] + alpha_T[256] (hat)
            out[b] =
                -(logf(tot) + (float)ksum * 0.69314718055994531f + sred);
        }
    } else {
        stV[b * 64 + l] = make_float4(X.x, X.y, Y.x, Y.y);
        if (is63) {
            stScal[b] = make_float4(pS, sred, 0.0f, 0.0f);
            kint[b] = ksum;
        }
    }
}

// ---------------- fallback (ws too small): legacy eb-form scan -----------
__global__ __launch_bounds__(256) void ctc_prep0(const float* __restrict__ Y,
                                                 float* __restrict__ invb) {
    const int lane = threadIdx.x & 63;
    const int wslot = threadIdx.x >> 6;
    const int nw = gridDim.x * 4;
    for (int w = blockIdx.x * 4 + wslot; w < NB * NT; w += nw) {
        const float* row = Y + (size_t)w * NC;
        float4 v0 = *reinterpret_cast<const float4*>(row + lane * 4);
        float4 v1 = *reinterpret_cast<const float4*>(row + NC / 2 + lane * 4);
        float s = ((v0.x + v0.y) + (v0.z + v0.w)) +
                  ((v1.x + v1.y) + (v1.z + v1.w));
#pragma unroll
        for (int d = 1; d < 64; d <<= 1) s += __shfl_xor(s, d);
        if (lane == 0) invb[w] = 256.0f / (s + NC * EPSF);
    }
}

__global__ __launch_bounds__(64) void ctc_rec0(const float* __restrict__ A,
                                               const float* __restrict__ Bv,
                                               const int* __restrict__ y_true,
                                               float* __restrict__ out) {
    const int b = blockIdx.x;
    const int l = threadIdx.x;
    const int* lab = y_true + b * NL;

    int lab_m1 = (l == 0) ? -1 : lab[2 * l - 1];
    int lab0 = lab[2 * l];
    int lab1 = lab[2 * l + 1];
    float sk0 = (lab0 != lab_m1) ? 1.0f : 0.0f;
    float sk1 = (lab1 != lab0) ? 1.0f : 0.0f;

    float p0 = (l == 0) ? 1.0f : 0.0f;
    float p1 = 0.0f, p2 = 0.0f, p3 = 0.0f, pS = 0.0f;
    int ksum = 0;

    for (int t = 0; t < NT; t++) {
        const float* base = A + ((size_t)b * NT + t) * NC;
        float iv = Bv[b * NT + t];
        float eb = (base[NC - 1] + EPSF) * iv;
        float ex = (base[lab0] + EPSF) * iv;
        float ey = (base[lab1] + EPSF) * iv;
        float s3 = dpp_shr1(p3);
        float n0 = (p0 + s3) * eb;
        float n1 = (p1 + p0 + sk0 * s3) * ex;
        float n2 = (p2 + p1) * eb;
        float n3 = (p3 + p2 + sk1 * p1) * ey;
        pS = (pS + p3) * eb;
        p0 = n0; p1 = n1; p2 = n2; p3 = n3;
        if ((t & 15) == 15) {
            float m = fmaxf(fmaxf(p0, p1), fmaxf(p2, p3));
            m = fmaxf(m, (l == 63) ? pS : 0.0f);
            float mall = fmaxf(dpp_wave_max(m), 1e-30f);
            int e = (int)(__float_as_uint(mall) >> 23) - 127;
            float sc = __uint_as_float((uint32)(127 - e) << 23);
            p0 *= sc; p1 *= sc; p2 *= sc; p3 *= sc; pS *= sc;
            ksum += e;
        }
    }

    if (l == 63) {
        float tot = p3 + pS;
        out[b] = -(logf(tot) + (float)(ksum - 8192) * 0.69314718055994531f);
    }
}

extern "C" void kernel_launch(void* const* d_in, const int* in_sizes, int n_in,
                              void* d_out, int out_size, void* d_ws, size_t ws_size,
                              hipStream_t stream) {
    const int* y_true = (const int*)d_in[0];
    const float* y_pred = (const float*)d_in[1];
    float* out = (float*)d_out;

    const size_t qring_b = 2 * SLOTF * sizeof(float);        // 16 MiB
    const size_t eb_b = (size_t)NB * NT * sizeof(float);     // 256 KiB
    const size_t stV_b = (size_t)NB * 64 * sizeof(float4);   // 64 KiB
    const size_t stS_b = (size_t)NB * sizeof(float4);        // 1 KiB
    const size_t kint_b = (size_t)NB * sizeof(int);
    const size_t need = qring_b + eb_b + stV_b + stS_b + kint_b;

    if (ws_size >= need) {
        char* p = (char*)d_ws;
        float* qring = (float*)p;            p += qring_b;
        float* eblank = (float*)p;           p += eb_b;
        float4* stV = (float4*)p;            p += stV_b;
        float4* stScal = (float4*)p;         p += stS_b;
        int* kint = (int*)p;

        // k=0: prep phase 0 only (all 1024 blocks produce)
        ctc_phase<<<GRID, 256, 0, stream>>>(y_pred, y_true, qring, eblank,
                                            stV, stScal, kint, out, -1, 0);
        // k=1..P-1: scan phase k-1 (64 blocks) || prep phase k (960 blocks)
        for (int k = 1; k < P; ++k)
            ctc_phase<<<GRID, 256, 0, stream>>>(y_pred, y_true, qring,
                                                eblank, stV, stScal, kint,
                                                out, k - 1, k);
        // final: scan phase P-1 only (64 scanner blocks)
        ctc_phase<<<NB, 256, 0, stream>>>(y_pred, y_true, qring, eblank,
                                          stV, stScal, kint, out, P - 1, P);
    } else {
        float* invb = (float*)d_ws;
        ctc_prep0<<<2048, 256, 0, stream>>>(y_pred, invb);
        ctc_rec0<<<NB, 64, 0, stream>>>(y_pred, invb, y_true, out);
    }
}